// Round 1
// baseline (308.572 us; speedup 1.0000x reference)
//
#include <hip/hip_runtime.h>

#define S_LEN 2048
#define DM 1024
#define NH 16
#define HD 64
#define QKV_LD 3072

using f32x4 = __attribute__((ext_vector_type(4))) float;
using s16x8 = __attribute__((ext_vector_type(8))) short;

__device__ __forceinline__ unsigned short f2bf(float f) {
  union { float f; unsigned u; } v; v.f = f;
  unsigned r = v.u + 0x7fffu + ((v.u >> 16) & 1u);
  return (unsigned short)(r >> 16);
}

__device__ __forceinline__ void gload_lds16(const void* g, void* l) {
  __builtin_amdgcn_global_load_lds(
      (const __attribute__((address_space(1))) void*)g,
      (__attribute__((address_space(3))) void*)l, 16, 0, 0);
}

__global__ __launch_bounds__(256) void cvt_f32_bf16(const float* __restrict__ in,
                                                    unsigned short* __restrict__ out,
                                                    int n) {
  int i = (blockIdx.x * 256 + threadIdx.x) * 8;
  if (i >= n) return;
  float4 a = *(const float4*)(in + i);
  float4 b = *(const float4*)(in + i + 4);
  s16x8 o;
  o[0] = f2bf(a.x); o[1] = f2bf(a.y); o[2] = f2bf(a.z); o[3] = f2bf(a.w);
  o[4] = f2bf(b.x); o[5] = f2bf(b.y); o[6] = f2bf(b.z); o[7] = f2bf(b.w);
  *(s16x8*)(out + i) = o;
}

// C[M,N] = A[M,K] * W[N,K]^T, bf16 in, bf16 or f32 out. 128x128 tile, BK=64,
// 4 waves (2x2), 16x16x32 MFMA, global_load_lds staging (m97 structure).
template <bool OUT_F32>
__global__ __launch_bounds__(256, 2) void gemm_bt(const unsigned short* __restrict__ A,
                                                  const unsigned short* __restrict__ W,
                                                  void* __restrict__ Cout,
                                                  int M, int N, int K, int nbn) {
  __shared__ unsigned short As[128 * 64];
  __shared__ unsigned short Bs[128 * 64];
  const int bm = blockIdx.x / nbn, bn = blockIdx.x % nbn;
  const int tid = threadIdx.x;
  const int w = tid >> 6, lane = tid & 63;
  const int wr = w >> 1, wc = w & 1;
  const int lr = lane & 15, lk = lane >> 4;
  const int m0 = bm * 128, n0 = bn * 128;
  f32x4 acc[4][4] = {};

  for (int k0 = 0; k0 < K; k0 += 64) {
#pragma unroll
    for (int i = 0; i < 4; ++i) {
      const int base = i * 4096 + w * 1024;  // wave-uniform byte offset in 16KB tile
      const int boff = base + lane * 16;     // this lane's bytes (HW: base + lane*16)
      const int row = boff >> 7;             // 128 B per row (64 bf16)
      const int col = (boff >> 1) & 63;
      gload_lds16(A + (size_t)(m0 + row) * K + k0 + col, (char*)As + base);
      gload_lds16(W + (size_t)(n0 + row) * K + k0 + col, (char*)Bs + base);
    }
    __syncthreads();  // compiler emits vmcnt(0) drain before barrier
#pragma unroll
    for (int kk = 0; kk < 2; ++kk) {
      s16x8 af[4], bfr[4];
#pragma unroll
      for (int m = 0; m < 4; ++m)
        af[m] = *(const s16x8*)((const char*)As + (wr * 64 + m * 16 + lr) * 128 + kk * 64 + lk * 16);
#pragma unroll
      for (int n = 0; n < 4; ++n)
        bfr[n] = *(const s16x8*)((const char*)Bs + (wc * 64 + n * 16 + lr) * 128 + kk * 64 + lk * 16);
#pragma unroll
      for (int m = 0; m < 4; ++m)
#pragma unroll
        for (int n = 0; n < 4; ++n)
          acc[m][n] = __builtin_amdgcn_mfma_f32_16x16x32_bf16(af[m], bfr[n], acc[m][n], 0, 0, 0);
    }
    __syncthreads();
  }
  // C/D layout: col = lane&15, row = (lane>>4)*4 + reg (m89-verified)
#pragma unroll
  for (int m = 0; m < 4; ++m)
#pragma unroll
    for (int n = 0; n < 4; ++n)
#pragma unroll
      for (int r = 0; r < 4; ++r) {
        const int row = m0 + wr * 64 + m * 16 + lk * 4 + r;
        const int col = n0 + wc * 64 + n * 16 + lr;
        if (OUT_F32)
          ((float*)Cout)[(size_t)row * N + col] = acc[m][n][r];
        else
          ((unsigned short*)Cout)[(size_t)row * N + col] = f2bf(acc[m][n][r]);
      }
}

// Flash attention, causal. qkv: [B*S][3072] bf16 (Q|K|V per head inside).
// Block: 4 waves; each wave owns 16 q-rows; block = 64-row q-tile. KV tile = 64.
__global__ __launch_bounds__(256, 2) void attn_fwd(const unsigned short* __restrict__ qkv,
                                                   unsigned short* __restrict__ aout) {
  __shared__ unsigned short Vt[64][72];        // V^T tile, pad 72 (2-way = free)
  __shared__ unsigned short Pbuf[4][16][72];   // per-wave P re-layout buffer
  const int blk = blockIdx.x;
  const int qt = blk & 31;
  const int bh = blk >> 5;
  const int h = bh & 15, b = bh >> 4;
  const int tid = threadIdx.x, w = tid >> 6, lane = tid & 63;
  const int lr = lane & 15, lk = lane >> 4;
  const int qb = qt * 64 + w * 16;
  const size_t rowbase = (size_t)b * S_LEN;

  // Q fragments held in registers for the whole kernel
  s16x8 qf[2];
#pragma unroll
  for (int dk = 0; dk < 2; ++dk)
    qf[dk] = *(const s16x8*)(qkv + (rowbase + qb + lr) * QKV_LD + h * HD + dk * 32 + lk * 8);

  f32x4 oacc[4] = {};
  float mrow[4], lsum[4];
#pragma unroll
  for (int r = 0; r < 4; ++r) { mrow[r] = -1e30f; lsum[r] = 0.f; }

  for (int t = 0; t <= qt; ++t) {
    const int k0 = t * 64;
    __syncthreads();  // protect previous Vt reads before overwrite
    // stage V^T: thread covers V[k=c&63][dbase..dbase+8)
#pragma unroll
    for (int i = 0; i < 2; ++i) {
      const int c = tid + i * 256;
      const int krow = c & 63, dbase = (c >> 6) * 8;
      s16x8 v = *(const s16x8*)(qkv + (rowbase + k0 + krow) * QKV_LD + 2 * DM + h * HD + dbase);
#pragma unroll
      for (int j = 0; j < 8; ++j) Vt[dbase + j][krow] = v[j];
    }
    __syncthreads();

    // S = Q K^T (K fragments straight from global; L2-resident)
    f32x4 sf[4];
#pragma unroll
    for (int n = 0; n < 4; ++n) {
      f32x4 s = {};
#pragma unroll
      for (int dk = 0; dk < 2; ++dk) {
        s16x8 kf = *(const s16x8*)(qkv + (rowbase + k0 + n * 16 + lr) * QKV_LD + DM + h * HD + dk * 32 + lk * 8);
        s = __builtin_amdgcn_mfma_f32_16x16x32_bf16(qf[dk], kf, s, 0, 0, 0);
      }
#pragma unroll
      for (int r = 0; r < 4; ++r) sf[n][r] = s[r] * 0.125f;
    }
    // causal mask on diagonal tile: S row q = qb + lk*4 + r, col k = k0 + n*16 + lr
    if (t == qt) {
#pragma unroll
      for (int n = 0; n < 4; ++n)
#pragma unroll
        for (int r = 0; r < 4; ++r)
          if (k0 + n * 16 + lr > qb + lk * 4 + r) sf[n][r] = -1e30f;
    }
    // online softmax: row stats across 16 lanes of the group
    float rs[4];
#pragma unroll
    for (int r = 0; r < 4; ++r) {
      float v = fmaxf(fmaxf(sf[0][r], sf[1][r]), fmaxf(sf[2][r], sf[3][r]));
      v = fmaxf(v, __shfl_xor(v, 1));
      v = fmaxf(v, __shfl_xor(v, 2));
      v = fmaxf(v, __shfl_xor(v, 4));
      v = fmaxf(v, __shfl_xor(v, 8));
      const float mn = fmaxf(mrow[r], v);
      const float al = __expf(mrow[r] - mn);
      mrow[r] = mn;
      lsum[r] *= al;
#pragma unroll
      for (int n = 0; n < 4; ++n) oacc[n][r] *= al;
      rs[r] = 0.f;
    }
#pragma unroll
    for (int n = 0; n < 4; ++n)
#pragma unroll
      for (int r = 0; r < 4; ++r) {
        float p = __expf(sf[n][r] - mrow[r]);
        sf[n][r] = p;
        rs[r] += p;
      }
#pragma unroll
    for (int r = 0; r < 4; ++r) {
      float v = rs[r];
      v += __shfl_xor(v, 1);
      v += __shfl_xor(v, 2);
      v += __shfl_xor(v, 4);
      v += __shfl_xor(v, 8);
      lsum[r] += v;
    }
    // P: C-frag layout -> LDS -> A-frag layout (wave-local, compiler orders lgkmcnt)
#pragma unroll
    for (int n = 0; n < 4; ++n)
#pragma unroll
      for (int r = 0; r < 4; ++r)
        Pbuf[w][lk * 4 + r][n * 16 + lr] = f2bf(sf[n][r]);
    // O += P V
#pragma unroll
    for (int kk = 0; kk < 2; ++kk) {
      s16x8 pf = *(const s16x8*)&Pbuf[w][lr][kk * 32 + lk * 8];
#pragma unroll
      for (int n = 0; n < 4; ++n) {
        s16x8 vf = *(const s16x8*)&Vt[n * 16 + lr][kk * 32 + lk * 8];
        oacc[n] = __builtin_amdgcn_mfma_f32_16x16x32_bf16(pf, vf, oacc[n], 0, 0, 0);
      }
    }
  }
  // epilogue: O/l -> attn buffer [B*S][1024] bf16
#pragma unroll
  for (int n = 0; n < 4; ++n)
#pragma unroll
    for (int r = 0; r < 4; ++r) {
      float o = oacc[n][r] / lsum[r];
      aout[(rowbase + qb + lk * 4 + r) * DM + h * HD + n * 16 + lr] = f2bf(o);
    }
}

extern "C" void kernel_launch(void* const* d_in, const int* in_sizes, int n_in,
                              void* d_out, int out_size, void* d_ws, size_t ws_size,
                              hipStream_t stream) {
  const float* x = (const float*)d_in[0];      // [2,2048,1024]
  const float* wqkv = (const float*)d_in[1];   // [3072,1024]
  const float* wproj = (const float*)d_in[2];  // [1024,1024]
  float* out = (float*)d_out;                  // [2,2048,1024] f32

  char* ws = (char*)d_ws;
  unsigned short* xb = (unsigned short*)ws;                    // 4096*1024 bf16 (8 MB)
  unsigned short* wqkvb = (unsigned short*)(ws + (8u << 20));  // 3072*1024 (6 MB)
  unsigned short* wprojb = (unsigned short*)(ws + (14u << 20)); // 1024*1024 (2 MB)
  unsigned short* qkvb = (unsigned short*)(ws + (16u << 20));  // 4096*3072 (24 MB)
  unsigned short* attnb = (unsigned short*)(ws + (40u << 20)); // 4096*1024 (8 MB)

  cvt_f32_bf16<<<2048, 256, 0, stream>>>(x, xb, 4096 * 1024);
  cvt_f32_bf16<<<1536, 256, 0, stream>>>(wqkv, wqkvb, 3072 * 1024);
  cvt_f32_bf16<<<512, 256, 0, stream>>>(wproj, wprojb, 1024 * 1024);

  gemm_bt<false><<<32 * 24, 256, 0, stream>>>(xb, wqkvb, qkvb, 4096, 3072, 1024, 24);
  attn_fwd<<<2 * 16 * 32, 256, 0, stream>>>(qkvb, attnb);
  gemm_bt<true><<<32 * 8, 256, 0, stream>>>(attnb, wprojb, out, 4096, 1024, 1024, 8);
}

// Round 2
// 294.684 us; speedup vs baseline: 1.0471x; 1.0471x over previous
//
#include <hip/hip_runtime.h>

#define S_LEN 2048
#define DM 1024
#define NH 16
#define HD 64
#define QKV_LD 3072

using f32x4 = __attribute__((ext_vector_type(4))) float;
using s16x8 = __attribute__((ext_vector_type(8))) short;

__device__ __forceinline__ unsigned short f2bf(float f) {
  union { float f; unsigned u; } v; v.f = f;
  unsigned r = v.u + 0x7fffu + ((v.u >> 16) & 1u);
  return (unsigned short)(r >> 16);
}

__device__ __forceinline__ void gload_lds16(const void* g, void* l) {
  __builtin_amdgcn_global_load_lds(
      (const __attribute__((address_space(1))) void*)g,
      (__attribute__((address_space(3))) void*)l, 16, 0, 0);
}

__global__ __launch_bounds__(256) void cvt_f32_bf16(const float* __restrict__ in,
                                                    unsigned short* __restrict__ out,
                                                    int n) {
  int i = (blockIdx.x * 256 + threadIdx.x) * 8;
  if (i >= n) return;
  float4 a = *(const float4*)(in + i);
  float4 b = *(const float4*)(in + i + 4);
  s16x8 o;
  o[0] = f2bf(a.x); o[1] = f2bf(a.y); o[2] = f2bf(a.z); o[3] = f2bf(a.w);
  o[4] = f2bf(b.x); o[5] = f2bf(b.y); o[6] = f2bf(b.z); o[7] = f2bf(b.w);
  *(s16x8*)(out + i) = o;
}

// C[M,N] = A[M,K] * W[N,K]^T, bf16 in, bf16 or f32 out. 128x128 tile, BK=64,
// 4 waves (2x2), 16x16x32 MFMA, global_load_lds staging (m97 structure).
template <bool OUT_F32>
__global__ __launch_bounds__(256, 2) void gemm_bt(const unsigned short* __restrict__ A,
                                                  const unsigned short* __restrict__ W,
                                                  void* __restrict__ Cout,
                                                  int M, int N, int K, int nbn) {
  __shared__ unsigned short As[128 * 64];
  __shared__ unsigned short Bs[128 * 64];
  const int bm = blockIdx.x / nbn, bn = blockIdx.x % nbn;
  const int tid = threadIdx.x;
  const int w = tid >> 6, lane = tid & 63;
  const int wr = w >> 1, wc = w & 1;
  const int lr = lane & 15, lk = lane >> 4;
  const int m0 = bm * 128, n0 = bn * 128;
  f32x4 acc[4][4] = {};

  for (int k0 = 0; k0 < K; k0 += 64) {
#pragma unroll
    for (int i = 0; i < 4; ++i) {
      const int base = i * 4096 + w * 1024;  // wave-uniform byte offset in 16KB tile
      const int boff = base + lane * 16;     // this lane's bytes (HW: base + lane*16)
      const int row = boff >> 7;             // 128 B per row (64 bf16)
      const int col = (boff >> 1) & 63;
      gload_lds16(A + (size_t)(m0 + row) * K + k0 + col, (char*)As + base);
      gload_lds16(W + (size_t)(n0 + row) * K + k0 + col, (char*)Bs + base);
    }
    __syncthreads();
#pragma unroll
    for (int kk = 0; kk < 2; ++kk) {
      s16x8 af[4], bfr[4];
#pragma unroll
      for (int m = 0; m < 4; ++m)
        af[m] = *(const s16x8*)((const char*)As + (wr * 64 + m * 16 + lr) * 128 + kk * 64 + lk * 16);
#pragma unroll
      for (int n = 0; n < 4; ++n)
        bfr[n] = *(const s16x8*)((const char*)Bs + (wc * 64 + n * 16 + lr) * 128 + kk * 64 + lk * 16);
#pragma unroll
      for (int m = 0; m < 4; ++m)
#pragma unroll
        for (int n = 0; n < 4; ++n)
          acc[m][n] = __builtin_amdgcn_mfma_f32_16x16x32_bf16(af[m], bfr[n], acc[m][n], 0, 0, 0);
    }
    __syncthreads();
  }
#pragma unroll
  for (int m = 0; m < 4; ++m)
#pragma unroll
    for (int n = 0; n < 4; ++n)
#pragma unroll
      for (int r = 0; r < 4; ++r) {
        const int row = m0 + wr * 64 + m * 16 + lk * 4 + r;
        const int col = n0 + wc * 64 + n * 16 + lr;
        if (OUT_F32)
          ((float*)Cout)[(size_t)row * N + col] = acc[m][n][r];
        else
          ((unsigned short*)Cout)[(size_t)row * N + col] = f2bf(acc[m][n][r]);
      }
}

// Transpose V out of qkv into VT[bh][d][s] so attention needs no in-loop
// transpose staging (PV B-frags become contiguous 16B global loads).
__global__ __launch_bounds__(256) void vtrans(const unsigned short* __restrict__ qkv,
                                              unsigned short* __restrict__ vt) {
  __shared__ unsigned short T[64][65];  // pad 65: transpose writes ~2-way (free)
  const int blk = blockIdx.x;           // bh*32 + st
  const int st = blk & 31, bh = blk >> 5;
  const int h = bh & 15, b = bh >> 4;
  const int s0 = st * 64;
  const int tid = threadIdx.x;
#pragma unroll
  for (int i = 0; i < 2; ++i) {
    const int idx = tid + i * 256;
    const int sy = idx >> 3, tx = idx & 7;
    s16x8 v = *(const s16x8*)(qkv + (size_t)(b * S_LEN + s0 + sy) * QKV_LD + 2 * DM + h * HD + tx * 8);
#pragma unroll
    for (int j = 0; j < 8; ++j) T[tx * 8 + j][sy] = v[j];
  }
  __syncthreads();
#pragma unroll
  for (int i = 0; i < 2; ++i) {
    const int idx = tid + i * 256;
    const int d = idx >> 3, tx = idx & 7;
    s16x8 v;
#pragma unroll
    for (int j = 0; j < 8; ++j) v[j] = T[d][tx * 8 + j];
    *(s16x8*)(vt + (size_t)bh * (HD * S_LEN) + (size_t)d * S_LEN + s0 + tx * 8) = v;
  }
}

// Flash attention, causal, barrier-free t-loop. 4 waves/block, each wave owns
// 16 q-rows; K and V^T fragments read straight from global (L2-resident).
__global__ __launch_bounds__(256, 4) void attn_fwd(const unsigned short* __restrict__ qkv,
                                                   const unsigned short* __restrict__ vt,
                                                   unsigned short* __restrict__ aout) {
  __shared__ unsigned short Pbuf[4][16][72];  // per-wave P re-layout (wave-local)
  const int blk = blockIdx.x;
  const int bh = blk & 31;
  const int qt = (31 - (blk >> 5) + bh) & 31;  // heavy-first, decorrelated across bh
  const int h = bh & 15, b = bh >> 4;
  const int tid = threadIdx.x, w = tid >> 6, lane = tid & 63;
  const int lr = lane & 15, lk = lane >> 4;
  const int qb = qt * 64 + w * 16;
  const size_t rowbase = (size_t)b * S_LEN;
  const unsigned short* vbase = vt + (size_t)bh * (HD * S_LEN);

  // Q fragments in registers, pre-scaled by 2^-3 (exact bf16 exponent decrement)
  s16x8 qf[2];
#pragma unroll
  for (int dk = 0; dk < 2; ++dk) {
    s16x8 q = *(const s16x8*)(qkv + (rowbase + qb + lr) * QKV_LD + h * HD + dk * 32 + lk * 8);
#pragma unroll
    for (int j = 0; j < 8; ++j) {
      unsigned short u = (unsigned short)q[j];
      if (u & 0x7f80u) u -= 0x0180u;  // *0.125, skip zero/denormal
      q[j] = (short)u;
    }
    qf[dk] = q;
  }

  f32x4 oacc[4] = {};
  float mrow[4], lsum[4];
#pragma unroll
  for (int r = 0; r < 4; ++r) { mrow[r] = -1e30f; lsum[r] = 0.f; }

  for (int t = 0; t <= qt; ++t) {
    const int k0 = t * 64;
    // S = Q K^T
    f32x4 sf[4];
#pragma unroll
    for (int n = 0; n < 4; ++n) {
      if (t < qt || n <= w) {
        f32x4 s = {};
#pragma unroll
        for (int dk = 0; dk < 2; ++dk) {
          s16x8 kf = *(const s16x8*)(qkv + (rowbase + k0 + n * 16 + lr) * QKV_LD + DM + h * HD + dk * 32 + lk * 8);
          s = __builtin_amdgcn_mfma_f32_16x16x32_bf16(qf[dk], kf, s, 0, 0, 0);
        }
        sf[n] = s;
        if (t == qt && n == w) {  // diagonal 16x16 subtile: per-element mask
#pragma unroll
          for (int r = 0; r < 4; ++r)
            if (n * 16 + lr > w * 16 + lk * 4 + r) sf[n][r] = -1e30f;
        }
      } else {
#pragma unroll
        for (int r = 0; r < 4; ++r) sf[n][r] = -1e30f;  // fully above diagonal
      }
    }
    // per-row tile max (16-lane group reduce)
    float pm[4];
#pragma unroll
    for (int r = 0; r < 4; ++r) {
      float v = fmaxf(fmaxf(sf[0][r], sf[1][r]), fmaxf(sf[2][r], sf[3][r]));
      v = fmaxf(v, __shfl_xor(v, 1));
      v = fmaxf(v, __shfl_xor(v, 2));
      v = fmaxf(v, __shfl_xor(v, 4));
      v = fmaxf(v, __shfl_xor(v, 8));
      pm[r] = v;
    }
    // defer-max (T13): only rescale when some row's max grew past threshold 8
    const bool need = (pm[0] > mrow[0] + 8.f) | (pm[1] > mrow[1] + 8.f) |
                      (pm[2] > mrow[2] + 8.f) | (pm[3] > mrow[3] + 8.f);
    if (__any(need)) {
#pragma unroll
      for (int r = 0; r < 4; ++r) {
        const float mn = fmaxf(mrow[r], pm[r]);
        const float al = __expf(mrow[r] - mn);
        mrow[r] = mn;
        lsum[r] *= al;
#pragma unroll
        for (int n = 0; n < 4; ++n) oacc[n][r] *= al;
      }
    }
    float rs[4] = {0.f, 0.f, 0.f, 0.f};
#pragma unroll
    for (int n = 0; n < 4; ++n)
#pragma unroll
      for (int r = 0; r < 4; ++r) {
        const float p = __expf(sf[n][r] - mrow[r]);
        sf[n][r] = p;
        rs[r] += p;
      }
#pragma unroll
    for (int r = 0; r < 4; ++r) {
      float v = rs[r];
      v += __shfl_xor(v, 1);
      v += __shfl_xor(v, 2);
      v += __shfl_xor(v, 4);
      v += __shfl_xor(v, 8);
      lsum[r] += v;
    }
    // P: C-frag -> LDS -> A-frag (wave-local, no barrier)
#pragma unroll
    for (int n = 0; n < 4; ++n)
#pragma unroll
      for (int r = 0; r < 4; ++r)
        Pbuf[w][lk * 4 + r][n * 16 + lr] = f2bf(sf[n][r]);
    // O += P V  (V^T rows straight from global)
#pragma unroll
    for (int kk = 0; kk < 2; ++kk) {
      s16x8 pf = *(const s16x8*)&Pbuf[w][lr][kk * 32 + lk * 8];
#pragma unroll
      for (int n = 0; n < 4; ++n) {
        s16x8 vf = *(const s16x8*)(vbase + (size_t)(n * 16 + lr) * S_LEN + k0 + kk * 32 + lk * 8);
        oacc[n] = __builtin_amdgcn_mfma_f32_16x16x32_bf16(pf, vf, oacc[n], 0, 0, 0);
      }
    }
  }
#pragma unroll
  for (int n = 0; n < 4; ++n)
#pragma unroll
    for (int r = 0; r < 4; ++r) {
      const float o = oacc[n][r] / lsum[r];
      aout[(rowbase + qb + lk * 4 + r) * DM + h * HD + n * 16 + lr] = f2bf(o);
    }
}

extern "C" void kernel_launch(void* const* d_in, const int* in_sizes, int n_in,
                              void* d_out, int out_size, void* d_ws, size_t ws_size,
                              hipStream_t stream) {
  const float* x = (const float*)d_in[0];      // [2,2048,1024]
  const float* wqkv = (const float*)d_in[1];   // [3072,1024]
  const float* wproj = (const float*)d_in[2];  // [1024,1024]
  float* out = (float*)d_out;                  // [2,2048,1024] f32

  char* ws = (char*)d_ws;
  // Overlay plan (48 MB total):
  //   [0,8)   xb      (dead after gemm1)      \
  //   [8,14)  wqkvb   (dead after gemm1)       }  vtb = [0,16) written by vtrans
  //   [14,16) wprojb  (written AFTER attn)    /
  //   [16,40) qkvb
  //   [40,48) attnb
  unsigned short* xb = (unsigned short*)ws;
  unsigned short* wqkvb = (unsigned short*)(ws + (8u << 20));
  unsigned short* wprojb = (unsigned short*)(ws + (14u << 20));
  unsigned short* vtb = (unsigned short*)ws;
  unsigned short* qkvb = (unsigned short*)(ws + (16u << 20));
  unsigned short* attnb = (unsigned short*)(ws + (40u << 20));

  cvt_f32_bf16<<<2048, 256, 0, stream>>>(x, xb, 4096 * 1024);
  cvt_f32_bf16<<<1536, 256, 0, stream>>>(wqkv, wqkvb, 3072 * 1024);

  gemm_bt<false><<<32 * 24, 256, 0, stream>>>(xb, wqkvb, qkvb, 4096, 3072, 1024, 24);
  vtrans<<<1024, 256, 0, stream>>>(qkvb, vtb);          // clobbers xb/wqkvb (dead)
  attn_fwd<<<1024, 256, 0, stream>>>(qkvb, vtb, attnb);
  cvt_f32_bf16<<<512, 256, 0, stream>>>(wproj, wprojb, 1024 * 1024);  // vtb dead now
  gemm_bt<true><<<32 * 8, 256, 0, stream>>>(attnb, wprojb, out, 4096, 1024, 1024, 8);
}

// Round 3
// 274.756 us; speedup vs baseline: 1.1231x; 1.0725x over previous
//
#include <hip/hip_runtime.h>

#define S_LEN 2048
#define DM 1024
#define NH 16
#define HD 64
#define QKV_LD 3072

using f32x4 = __attribute__((ext_vector_type(4))) float;
using s16x8 = __attribute__((ext_vector_type(8))) short;

__device__ __forceinline__ unsigned short f2bf(float f) {
  union { float f; unsigned u; } v; v.f = f;
  unsigned r = v.u + 0x7fffu + ((v.u >> 16) & 1u);
  return (unsigned short)(r >> 16);
}

__device__ __forceinline__ float bf2f(unsigned short u) {
  union { unsigned u; float f; } v; v.u = ((unsigned)u) << 16;
  return v.f;
}

__device__ __forceinline__ void gload_lds16(const void* g, void* l) {
  __builtin_amdgcn_global_load_lds(
      (const __attribute__((address_space(1))) void*)g,
      (__attribute__((address_space(3))) void*)l, 16, 0, 0);
}

__global__ __launch_bounds__(256) void cvt_f32_bf16(const float* __restrict__ in,
                                                    unsigned short* __restrict__ out,
                                                    int n) {
  int i = (blockIdx.x * 256 + threadIdx.x) * 8;
  if (i >= n) return;
  float4 a = *(const float4*)(in + i);
  float4 b = *(const float4*)(in + i + 4);
  s16x8 o;
  o[0] = f2bf(a.x); o[1] = f2bf(a.y); o[2] = f2bf(a.z); o[3] = f2bf(a.w);
  o[4] = f2bf(b.x); o[5] = f2bf(b.y); o[6] = f2bf(b.z); o[7] = f2bf(b.w);
  *(s16x8*)(out + i) = o;
}

// C[M,N] = A[M,K] * W[N,K]^T, bf16 in, bf16 or f32 out. 128x128 tile, BK=64,
// 4 waves (2x2), 16x16x32 MFMA, global_load_lds staging (m97 structure).
template <bool OUT_F32>
__global__ __launch_bounds__(256, 2) void gemm_bt(const unsigned short* __restrict__ A,
                                                  const unsigned short* __restrict__ W,
                                                  void* __restrict__ Cout,
                                                  int M, int N, int K, int nbn) {
  __shared__ unsigned short As[128 * 64];
  __shared__ unsigned short Bs[128 * 64];
  const int bm = blockIdx.x / nbn, bn = blockIdx.x % nbn;
  const int tid = threadIdx.x;
  const int w = tid >> 6, lane = tid & 63;
  const int wr = w >> 1, wc = w & 1;
  const int lr = lane & 15, lk = lane >> 4;
  const int m0 = bm * 128, n0 = bn * 128;
  f32x4 acc[4][4] = {};

  for (int k0 = 0; k0 < K; k0 += 64) {
#pragma unroll
    for (int i = 0; i < 4; ++i) {
      const int base = i * 4096 + w * 1024;
      const int boff = base + lane * 16;
      const int row = boff >> 7;
      const int col = (boff >> 1) & 63;
      gload_lds16(A + (size_t)(m0 + row) * K + k0 + col, (char*)As + base);
      gload_lds16(W + (size_t)(n0 + row) * K + k0 + col, (char*)Bs + base);
    }
    __syncthreads();
#pragma unroll
    for (int kk = 0; kk < 2; ++kk) {
      s16x8 af[4], bfr[4];
#pragma unroll
      for (int m = 0; m < 4; ++m)
        af[m] = *(const s16x8*)((const char*)As + (wr * 64 + m * 16 + lr) * 128 + kk * 64 + lk * 16);
#pragma unroll
      for (int n = 0; n < 4; ++n)
        bfr[n] = *(const s16x8*)((const char*)Bs + (wc * 64 + n * 16 + lr) * 128 + kk * 64 + lk * 16);
#pragma unroll
      for (int m = 0; m < 4; ++m)
#pragma unroll
        for (int n = 0; n < 4; ++n)
          acc[m][n] = __builtin_amdgcn_mfma_f32_16x16x32_bf16(af[m], bfr[n], acc[m][n], 0, 0, 0);
    }
    __syncthreads();
  }
#pragma unroll
  for (int m = 0; m < 4; ++m)
#pragma unroll
    for (int n = 0; n < 4; ++n)
#pragma unroll
      for (int r = 0; r < 4; ++r) {
        const int row = m0 + wr * 64 + m * 16 + lk * 4 + r;
        const int col = n0 + wc * 64 + n * 16 + lr;
        if (OUT_F32)
          ((float*)Cout)[(size_t)row * N + col] = acc[m][n][r];
        else
          ((unsigned short*)Cout)[(size_t)row * N + col] = f2bf(acc[m][n][r]);
      }
}

// Transpose V out of qkv into VT[bh][d][s].
__global__ __launch_bounds__(256) void vtrans(const unsigned short* __restrict__ qkv,
                                              unsigned short* __restrict__ vt) {
  __shared__ unsigned short T[64][65];
  const int blk = blockIdx.x;
  const int st = blk & 31, bh = blk >> 5;
  const int h = bh & 15, b = bh >> 4;
  const int s0 = st * 64;
  const int tid = threadIdx.x;
#pragma unroll
  for (int i = 0; i < 2; ++i) {
    const int idx = tid + i * 256;
    const int sy = idx >> 3, tx = idx & 7;
    s16x8 v = *(const s16x8*)(qkv + (size_t)(b * S_LEN + s0 + sy) * QKV_LD + 2 * DM + h * HD + tx * 8);
#pragma unroll
    for (int j = 0; j < 8; ++j) T[tx * 8 + j][sy] = v[j];
  }
  __syncthreads();
#pragma unroll
  for (int i = 0; i < 2; ++i) {
    const int idx = tid + i * 256;
    const int d = idx >> 3, tx = idx & 7;
    s16x8 v;
#pragma unroll
    for (int j = 0; j < 8; ++j) v[j] = T[d][tx * 8 + j];
    *(s16x8*)(vt + (size_t)bh * (HD * S_LEN) + (size_t)d * S_LEN + s0 + tx * 8) = v;
  }
}

// Flash attention, causal. ONE wave per block (64 thr); wave owns 16 q-rows.
// K register-pipelined across t; V issued early each iteration (T14).
// Softmax in exp2 domain (log2e folded into Q scale).
__global__ __launch_bounds__(64, 3) void attn_fwd(const unsigned short* __restrict__ qkv,
                                                  const unsigned short* __restrict__ vt,
                                                  unsigned short* __restrict__ aout) {
  __shared__ unsigned short Pbuf[16][72];  // wave-local P re-layout
  const int blk = blockIdx.x;              // 4096 = 32 qt * 32 bh * 4 rowgroup
  const int qt = 31 - (blk >> 7);          // heavy tiles dispatched first
  const int inner = blk & 127;
  const int bh = inner >> 2, ws = inner & 3;
  const int h = bh & 15, b = bh >> 4;
  const int lane = threadIdx.x & 63;
  const int lr = lane & 15, lk = lane >> 4;
  const int qb = qt * 64 + ws * 16;
  const size_t rowbase = (size_t)b * S_LEN;
  const unsigned short* kbase = qkv + rowbase * QKV_LD + DM + h * HD;
  const unsigned short* vbase = vt + (size_t)bh * (HD * S_LEN);

  // Q fragments, scaled by 0.125*log2(e) so softmax runs in exp2 domain
  s16x8 qf[2];
#pragma unroll
  for (int dk = 0; dk < 2; ++dk) {
    s16x8 q = *(const s16x8*)(qkv + (rowbase + qb + lr) * QKV_LD + h * HD + dk * 32 + lk * 8);
#pragma unroll
    for (int j = 0; j < 8; ++j)
      q[j] = (short)f2bf(bf2f((unsigned short)q[j]) * 0.18033688011112042f);
    qf[dk] = q;
  }

  f32x4 oacc[4] = {};
  float mrow[4], lsum[4];
#pragma unroll
  for (int r = 0; r < 4; ++r) { mrow[r] = -1e30f; lsum[r] = 0.f; }

  // K prologue: tile 0 fragments into registers
  s16x8 kf[8], vf[8];
#pragma unroll
  for (int n = 0; n < 4; ++n)
#pragma unroll
    for (int dk = 0; dk < 2; ++dk)
      kf[n * 2 + dk] = *(const s16x8*)(kbase + (size_t)(n * 16 + lr) * QKV_LD + dk * 32 + lk * 8);

  for (int t = 0; t <= qt; ++t) {
    const int k0 = t * 64;
    // issue V(t) loads now; consumed after softmax (latency hidden)
#pragma unroll
    for (int n = 0; n < 4; ++n)
#pragma unroll
      for (int kk = 0; kk < 2; ++kk)
        vf[n * 2 + kk] = *(const s16x8*)(vbase + (size_t)(n * 16 + lr) * S_LEN + k0 + kk * 32 + lk * 8);

    // S = Q K^T from resident kf
    f32x4 sf[4];
#pragma unroll
    for (int n = 0; n < 4; ++n) {
      if (t < qt || n <= ws) {
        f32x4 s = {};
        s = __builtin_amdgcn_mfma_f32_16x16x32_bf16(qf[0], kf[n * 2 + 0], s, 0, 0, 0);
        s = __builtin_amdgcn_mfma_f32_16x16x32_bf16(qf[1], kf[n * 2 + 1], s, 0, 0, 0);
        sf[n] = s;
        if (t == qt && n == ws) {
#pragma unroll
          for (int r = 0; r < 4; ++r)
            if (n * 16 + lr > ws * 16 + lk * 4 + r) sf[n][r] = -1e30f;
        }
      } else {
#pragma unroll
        for (int r = 0; r < 4; ++r) sf[n][r] = -1e30f;
      }
    }

    // prefetch K(t+1) right after last kf use; hides under softmax+PV
    const int kn0 = k0 + (t < qt ? 64 : 0);
#pragma unroll
    for (int n = 0; n < 4; ++n)
#pragma unroll
      for (int dk = 0; dk < 2; ++dk)
        kf[n * 2 + dk] = *(const s16x8*)(kbase + (size_t)(kn0 + n * 16 + lr) * QKV_LD + dk * 32 + lk * 8);

    // per-row tile max (16-lane group reduce)
    float pm[4];
#pragma unroll
    for (int r = 0; r < 4; ++r) {
      float v = fmaxf(fmaxf(sf[0][r], sf[1][r]), fmaxf(sf[2][r], sf[3][r]));
      v = fmaxf(v, __shfl_xor(v, 1));
      v = fmaxf(v, __shfl_xor(v, 2));
      v = fmaxf(v, __shfl_xor(v, 4));
      v = fmaxf(v, __shfl_xor(v, 8));
      pm[r] = v;
    }
    // defer-max (T13, exp2 domain, thr 8 -> P bounded by 256)
    const bool need = (pm[0] > mrow[0] + 8.f) | (pm[1] > mrow[1] + 8.f) |
                      (pm[2] > mrow[2] + 8.f) | (pm[3] > mrow[3] + 8.f);
    if (__any(need)) {
#pragma unroll
      for (int r = 0; r < 4; ++r) {
        const float mn = fmaxf(mrow[r], pm[r]);
        const float al = __builtin_amdgcn_exp2f(mrow[r] - mn);
        mrow[r] = mn;
        lsum[r] *= al;
#pragma unroll
        for (int n = 0; n < 4; ++n) oacc[n][r] *= al;
      }
    }
    float rs[4] = {0.f, 0.f, 0.f, 0.f};
#pragma unroll
    for (int n = 0; n < 4; ++n)
#pragma unroll
      for (int r = 0; r < 4; ++r) {
        const float p = __builtin_amdgcn_exp2f(sf[n][r] - mrow[r]);
        sf[n][r] = p;
        rs[r] += p;
      }
#pragma unroll
    for (int r = 0; r < 4; ++r) {
      float v = rs[r];
      v += __shfl_xor(v, 1);
      v += __shfl_xor(v, 2);
      v += __shfl_xor(v, 4);
      v += __shfl_xor(v, 8);
      lsum[r] += v;
    }
    // P: C-frag -> LDS -> A-frag (wave-local)
#pragma unroll
    for (int n = 0; n < 4; ++n)
#pragma unroll
      for (int r = 0; r < 4; ++r)
        Pbuf[lk * 4 + r][n * 16 + lr] = f2bf(sf[n][r]);
    // O += P V from resident vf
#pragma unroll
    for (int kk = 0; kk < 2; ++kk) {
      s16x8 pf = *(const s16x8*)&Pbuf[lr][kk * 32 + lk * 8];
#pragma unroll
      for (int n = 0; n < 4; ++n)
        oacc[n] = __builtin_amdgcn_mfma_f32_16x16x32_bf16(pf, vf[n * 2 + kk], oacc[n], 0, 0, 0);
    }
  }
#pragma unroll
  for (int r = 0; r < 4; ++r) {
    const float rl = __builtin_amdgcn_rcpf(lsum[r]);
#pragma unroll
    for (int n = 0; n < 4; ++n)
      aout[(rowbase + qb + lk * 4 + r) * DM + h * HD + n * 16 + lr] = f2bf(oacc[n][r] * rl);
  }
}

extern "C" void kernel_launch(void* const* d_in, const int* in_sizes, int n_in,
                              void* d_out, int out_size, void* d_ws, size_t ws_size,
                              hipStream_t stream) {
  const float* x = (const float*)d_in[0];      // [2,2048,1024]
  const float* wqkv = (const float*)d_in[1];   // [3072,1024]
  const float* wproj = (const float*)d_in[2];  // [1024,1024]
  float* out = (float*)d_out;                  // [2,2048,1024] f32

  char* ws = (char*)d_ws;
  unsigned short* xb = (unsigned short*)ws;                     // dead after gemm1
  unsigned short* wqkvb = (unsigned short*)(ws + (8u << 20));   // dead after gemm1
  unsigned short* wprojb = (unsigned short*)(ws + (14u << 20)); // written after attn
  unsigned short* vtb = (unsigned short*)ws;                    // overlays xb/wqkvb
  unsigned short* qkvb = (unsigned short*)(ws + (16u << 20));
  unsigned short* attnb = (unsigned short*)(ws + (40u << 20));

  cvt_f32_bf16<<<2048, 256, 0, stream>>>(x, xb, 4096 * 1024);
  cvt_f32_bf16<<<1536, 256, 0, stream>>>(wqkv, wqkvb, 3072 * 1024);

  gemm_bt<false><<<32 * 24, 256, 0, stream>>>(xb, wqkvb, qkvb, 4096, 3072, 1024, 24);
  vtrans<<<1024, 256, 0, stream>>>(qkvb, vtb);
  attn_fwd<<<4096, 64, 0, stream>>>(qkvb, vtb, attnb);
  cvt_f32_bf16<<<512, 256, 0, stream>>>(wproj, wprojb, 1024 * 1024);
  gemm_bt<true><<<32 * 8, 256, 0, stream>>>(attnb, wprojb, out, 4096, 1024, 1024, 8);
}

// Round 5
// 271.711 us; speedup vs baseline: 1.1357x; 1.0112x over previous
//
#include <hip/hip_runtime.h>

#define S_LEN 2048
#define DM 1024
#define NH 16
#define HD 64
#define QKV_LD 3072

using f32x4 = __attribute__((ext_vector_type(4))) float;
using s16x8 = __attribute__((ext_vector_type(8))) short;

__device__ __forceinline__ unsigned short f2bf(float f) {
  union { float f; unsigned u; } v; v.f = f;
  unsigned r = v.u + 0x7fffu + ((v.u >> 16) & 1u);
  return (unsigned short)(r >> 16);
}

__device__ __forceinline__ float bf2f(unsigned short u) {
  union { unsigned u; float f; } v; v.u = ((unsigned)u) << 16;
  return v.f;
}

__device__ __forceinline__ void gload_lds16(const void* g, void* l) {
  __builtin_amdgcn_global_load_lds(
      (const __attribute__((address_space(1))) void*)g,
      (__attribute__((address_space(3))) void*)l, 16, 0, 0);
}

__global__ __launch_bounds__(256) void cvt_f32_bf16(const float* __restrict__ in,
                                                    unsigned short* __restrict__ out,
                                                    int n) {
  int i = (blockIdx.x * 256 + threadIdx.x) * 8;
  if (i >= n) return;
  float4 a = *(const float4*)(in + i);
  float4 b = *(const float4*)(in + i + 4);
  s16x8 o;
  o[0] = f2bf(a.x); o[1] = f2bf(a.y); o[2] = f2bf(a.z); o[3] = f2bf(a.w);
  o[4] = f2bf(b.x); o[5] = f2bf(b.y); o[6] = f2bf(b.z); o[7] = f2bf(b.w);
  *(s16x8*)(out + i) = o;
}

// C[M,N] = A[M,K] * W[N,K]^T, bf16 in, bf16 or f32 out. 128x128 tile, BK=64,
// 4 waves (2x2), 16x16x32 MFMA, global_load_lds staging (m97 structure).
template <bool OUT_F32>
__global__ __launch_bounds__(256, 2) void gemm_bt(const unsigned short* __restrict__ A,
                                                  const unsigned short* __restrict__ W,
                                                  void* __restrict__ Cout,
                                                  int M, int N, int K, int nbn) {
  __shared__ unsigned short As[128 * 64];
  __shared__ unsigned short Bs[128 * 64];
  const int bm = blockIdx.x / nbn, bn = blockIdx.x % nbn;
  const int tid = threadIdx.x;
  const int w = tid >> 6, lane = tid & 63;
  const int wr = w >> 1, wc = w & 1;
  const int lr = lane & 15, lk = lane >> 4;
  const int m0 = bm * 128, n0 = bn * 128;
  f32x4 acc[4][4] = {};

  for (int k0 = 0; k0 < K; k0 += 64) {
#pragma unroll
    for (int i = 0; i < 4; ++i) {
      const int base = i * 4096 + w * 1024;
      const int boff = base + lane * 16;
      const int row = boff >> 7;
      const int col = (boff >> 1) & 63;
      gload_lds16(A + (size_t)(m0 + row) * K + k0 + col, (char*)As + base);
      gload_lds16(W + (size_t)(n0 + row) * K + k0 + col, (char*)Bs + base);
    }
    __syncthreads();
#pragma unroll
    for (int kk = 0; kk < 2; ++kk) {
      s16x8 af[4], bfr[4];
#pragma unroll
      for (int m = 0; m < 4; ++m)
        af[m] = *(const s16x8*)((const char*)As + (wr * 64 + m * 16 + lr) * 128 + kk * 64 + lk * 16);
#pragma unroll
      for (int n = 0; n < 4; ++n)
        bfr[n] = *(const s16x8*)((const char*)Bs + (wc * 64 + n * 16 + lr) * 128 + kk * 64 + lk * 16);
#pragma unroll
      for (int m = 0; m < 4; ++m)
#pragma unroll
        for (int n = 0; n < 4; ++n)
          acc[m][n] = __builtin_amdgcn_mfma_f32_16x16x32_bf16(af[m], bfr[n], acc[m][n], 0, 0, 0);
    }
    __syncthreads();
  }
#pragma unroll
  for (int m = 0; m < 4; ++m)
#pragma unroll
    for (int n = 0; n < 4; ++n)
#pragma unroll
      for (int r = 0; r < 4; ++r) {
        const int row = m0 + wr * 64 + m * 16 + lk * 4 + r;
        const int col = n0 + wc * 64 + n * 16 + lr;
        if (OUT_F32)
          ((float*)Cout)[(size_t)row * N + col] = acc[m][n][r];
        else
          ((unsigned short*)Cout)[(size_t)row * N + col] = f2bf(acc[m][n][r]);
      }
}

// Transpose V out of qkv into VT[bh][d][s].
__global__ __launch_bounds__(256) void vtrans(const unsigned short* __restrict__ qkv,
                                              unsigned short* __restrict__ vt) {
  __shared__ unsigned short T[64][65];
  const int blk = blockIdx.x;
  const int st = blk & 31, bh = blk >> 5;
  const int h = bh & 15, b = bh >> 4;
  const int s0 = st * 64;
  const int tid = threadIdx.x;
#pragma unroll
  for (int i = 0; i < 2; ++i) {
    const int idx = tid + i * 256;
    const int sy = idx >> 3, tx = idx & 7;
    s16x8 v = *(const s16x8*)(qkv + (size_t)(b * S_LEN + s0 + sy) * QKV_LD + 2 * DM + h * HD + tx * 8);
#pragma unroll
    for (int j = 0; j < 8; ++j) T[tx * 8 + j][sy] = v[j];
  }
  __syncthreads();
#pragma unroll
  for (int i = 0; i < 2; ++i) {
    const int idx = tid + i * 256;
    const int d = idx >> 3, tx = idx & 7;
    s16x8 v;
#pragma unroll
    for (int j = 0; j < 8; ++j) v[j] = T[d][tx * 8 + j];
    *(s16x8*)(vt + (size_t)bh * (HD * S_LEN) + (size_t)d * S_LEN + s0 + tx * 8) = v;
  }
}

// Flash attention, causal. Block = 16 q-rows, 4 waves split the KV range
// round-robin (t = w, w+4, ...) with private online-softmax state; merged
// once at the end through LDS. QK^T computed SWAPPED (mfma(K,Q) -> S^T) so
// each lane owns one q-row's 16 scores: row reduce = in-lane + 2 shfl.
__global__ __launch_bounds__(256, 4) void attn_fwd(const unsigned short* __restrict__ qkv,
                                                   const unsigned short* __restrict__ vt,
                                                   unsigned short* __restrict__ aout) {
  __shared__ float Osh[3][16][68];           // waves 1-3 partial O (pad 68: 2-way)
  __shared__ float Msh[3][16], Lsh[3][16];   // waves 1-3 stats (per q-row)
  __shared__ unsigned short Pbuf[4][16][72]; // per-wave P re-layout
  const int bid = blockIdx.x;
  const int rg = 127 - (bid >> 5);  // heavy rowgroups first
  const int bh = bid & 31;
  const int h = bh & 15, b = bh >> 4;
  const int tid = threadIdx.x, w = tid >> 6, lane = tid & 63;
  const int lr = lane & 15, lk = lane >> 4;
  const int qb = rg * 16;
  const int T = qb >> 6;   // last (diagonal) KV tile
  const int dn = rg & 3;   // diagonal 16-subtile within tile T
  const size_t rowbase = (size_t)b * S_LEN;
  const unsigned short* kbase = qkv + rowbase * QKV_LD + DM + h * HD;
  const unsigned short* vbase = vt + (size_t)bh * (HD * S_LEN);

  // Q fragments (B-operand), scaled by 0.125*log2(e) -> exp2-domain softmax
  s16x8 qf[2];
#pragma unroll
  for (int dk = 0; dk < 2; ++dk) {
    s16x8 q = *(const s16x8*)(qkv + (rowbase + qb + lr) * QKV_LD + h * HD + dk * 32 + lk * 8);
#pragma unroll
    for (int j = 0; j < 8; ++j)
      q[j] = (short)f2bf(bf2f((unsigned short)q[j]) * 0.18033688011112042f);
    qf[dk] = q;
  }

  f32x4 oacc[4] = {};
  float mr = -1e30f, ls = 0.f;

  for (int t = w; t <= T; t += 4) {
    const int k0 = t * 64;
    const bool diag = (t == T);
    // S^T = K Q^T : sf[n][r] = S[k = k0+n*16+lk*4+r][q = qb+lr]
    f32x4 sf[4];
#pragma unroll
    for (int n = 0; n < 4; ++n) {
      if (!diag || n <= dn) {
        s16x8 kf0 = *(const s16x8*)(kbase + (size_t)(k0 + n * 16 + lr) * QKV_LD + lk * 8);
        s16x8 kf1 = *(const s16x8*)(kbase + (size_t)(k0 + n * 16 + lr) * QKV_LD + 32 + lk * 8);
        f32x4 s = {};
        s = __builtin_amdgcn_mfma_f32_16x16x32_bf16(kf0, qf[0], s, 0, 0, 0);
        s = __builtin_amdgcn_mfma_f32_16x16x32_bf16(kf1, qf[1], s, 0, 0, 0);
        sf[n] = s;
      } else {
#pragma unroll
        for (int r = 0; r < 4; ++r) sf[n][r] = -1e30f;
      }
    }
    if (diag) {  // mask subtile dn: element (k=lk*4+r, q=lr) masked iff k > q
#pragma unroll
      for (int r = 0; r < 4; ++r)
        if (lk * 4 + r > lr) sf[dn][r] = -1e30f;
    }
    // row max: in-lane over 16 values + 2 shfl across lk-groups
    float pm = sf[0][0];
#pragma unroll
    for (int n = 0; n < 4; ++n)
#pragma unroll
      for (int r = 0; r < 4; ++r) pm = fmaxf(pm, sf[n][r]);
    pm = fmaxf(pm, __shfl_xor(pm, 16));
    pm = fmaxf(pm, __shfl_xor(pm, 32));
    // defer-max (T13, exp2 domain): rescale only when max grew past 8
    if (__any(pm > mr + 8.f)) {
      const float mn = fmaxf(mr, pm);
      const float al = __builtin_amdgcn_exp2f(mr - mn);
      mr = mn;
      ls *= al;
#pragma unroll
      for (int r = 0; r < 4; ++r) {
        const float alq = __shfl(al, lk * 4 + r);  // lr-domain -> O-row domain
#pragma unroll
        for (int n = 0; n < 4; ++n) oacc[n][r] *= alq;
      }
    }
    // P = exp2(S - m), in-lane row sum + 2 shfl
    float rs = 0.f;
#pragma unroll
    for (int n = 0; n < 4; ++n)
#pragma unroll
      for (int r = 0; r < 4; ++r) {
        const float p = __builtin_amdgcn_exp2f(sf[n][r] - mr);
        sf[n][r] = p;
        rs += p;
      }
    rs += __shfl_xor(rs, 16);
    rs += __shfl_xor(rs, 32);
    ls += rs;
    // pack P (positive: round-half-up == RNE sans ties) -> Pbuf[q=lr][k]
#pragma unroll
    for (int n = 0; n < 4; ++n) {
      union { float f; unsigned u; } c0, c1, c2, c3;
      c0.f = sf[n][0]; c1.f = sf[n][1]; c2.f = sf[n][2]; c3.f = sf[n][3];
      uint2 pk;
      pk.x = ((c0.u + 0x8000u) >> 16) | (((c1.u + 0x8000u) >> 16) << 16);
      pk.y = ((c2.u + 0x8000u) >> 16) | (((c3.u + 0x8000u) >> 16) << 16);
      *(uint2*)&Pbuf[w][lr][n * 16 + lk * 4] = pk;
    }
    // O += P V (A = P rows from Pbuf, B = V^T rows from global)
#pragma unroll
    for (int kk = 0; kk < 2; ++kk) {
      s16x8 pf = *(const s16x8*)&Pbuf[w][lr][kk * 32 + lk * 8];
#pragma unroll
      for (int n = 0; n < 4; ++n) {
        s16x8 vf = *(const s16x8*)(vbase + (size_t)(n * 16 + lr) * S_LEN + k0 + kk * 32 + lk * 8);
        oacc[n] = __builtin_amdgcn_mfma_f32_16x16x32_bf16(pf, vf, oacc[n], 0, 0, 0);
      }
    }
  }

  // merge 4 partial results (waves 1-3 -> LDS; wave 0 combines + stores)
  if (w > 0) {
    if (lane < 16) { Msh[w - 1][lane] = mr; Lsh[w - 1][lane] = ls; }
#pragma unroll
    for (int n = 0; n < 4; ++n)
#pragma unroll
      for (int r = 0; r < 4; ++r)
        Osh[w - 1][lk * 4 + r][n * 16 + lr] = oacc[n][r];
  }
  __syncthreads();
  if (w == 0) {
    const float m1 = Msh[0][lr], m2 = Msh[1][lr], m3 = Msh[2][lr];
    const float M = fmaxf(fmaxf(mr, m1), fmaxf(m2, m3));
    const float s0 = __builtin_amdgcn_exp2f(mr - M);
    const float s1 = __builtin_amdgcn_exp2f(m1 - M);
    const float s2 = __builtin_amdgcn_exp2f(m2 - M);
    const float s3 = __builtin_amdgcn_exp2f(m3 - M);
    const float L = ls * s0 + Lsh[0][lr] * s1 + Lsh[1][lr] * s2 + Lsh[2][lr] * s3;
#pragma unroll
    for (int r = 0; r < 4; ++r) {
      const int src = lk * 4 + r;
      const float s0q = __shfl(s0, src), s1q = __shfl(s1, src);
      const float s2q = __shfl(s2, src), s3q = __shfl(s3, src);
      const float rl = __builtin_amdgcn_rcpf(__shfl(L, src));
#pragma unroll
      for (int n = 0; n < 4; ++n) {
        const float o = oacc[n][r] * s0q + Osh[0][lk * 4 + r][n * 16 + lr] * s1q +
                        Osh[1][lk * 4 + r][n * 16 + lr] * s2q +
                        Osh[2][lk * 4 + r][n * 16 + lr] * s3q;
        aout[(rowbase + qb + lk * 4 + r) * DM + h * HD + n * 16 + lr] = f2bf(o * rl);
      }
    }
  }
}

extern "C" void kernel_launch(void* const* d_in, const int* in_sizes, int n_in,
                              void* d_out, int out_size, void* d_ws, size_t ws_size,
                              hipStream_t stream) {
  const float* x = (const float*)d_in[0];      // [2,2048,1024]
  const float* wqkv = (const float*)d_in[1];   // [3072,1024]
  const float* wproj = (const float*)d_in[2];  // [1024,1024]
  float* out = (float*)d_out;                  // [2,2048,1024] f32

  char* ws = (char*)d_ws;
  unsigned short* xb = (unsigned short*)ws;                     // dead after gemm1
  unsigned short* wqkvb = (unsigned short*)(ws + (8u << 20));   // dead after gemm1
  unsigned short* wprojb = (unsigned short*)(ws + (14u << 20)); // written after attn
  unsigned short* vtb = (unsigned short*)ws;                    // overlays xb/wqkvb
  unsigned short* qkvb = (unsigned short*)(ws + (16u << 20));
  unsigned short* attnb = (unsigned short*)(ws + (40u << 20));

  cvt_f32_bf16<<<2048, 256, 0, stream>>>(x, xb, 4096 * 1024);
  cvt_f32_bf16<<<1536, 256, 0, stream>>>(wqkv, wqkvb, 3072 * 1024);

  gemm_bt<false><<<32 * 24, 256, 0, stream>>>(xb, wqkvb, qkvb, 4096, 3072, 1024, 24);
  vtrans<<<1024, 256, 0, stream>>>(qkvb, vtb);
  attn_fwd<<<4096, 256, 0, stream>>>(qkvb, vtb, attnb);
  cvt_f32_bf16<<<512, 256, 0, stream>>>(wproj, wprojb, 1024 * 1024);
  gemm_bt<true><<<32 * 8, 256, 0, stream>>>(attnb, wprojb, out, 4096, 1024, 1024, 8);
}

// Round 6
// 188.472 us; speedup vs baseline: 1.6372x; 1.4417x over previous
//
#include <hip/hip_runtime.h>

#define S_LEN 2048
#define DM 1024
#define NH 16
#define HD 64
#define QKV_LD 3072

using f32x4 = __attribute__((ext_vector_type(4))) float;
using s16x8 = __attribute__((ext_vector_type(8))) short;

__device__ __forceinline__ unsigned short f2bf(float f) {
  union { float f; unsigned u; } v; v.f = f;
  unsigned r = v.u + 0x7fffu + ((v.u >> 16) & 1u);
  return (unsigned short)(r >> 16);
}

__device__ __forceinline__ float bf2f(unsigned short u) {
  union { unsigned u; float f; } v; v.u = ((unsigned)u) << 16;
  return v.f;
}

__device__ __forceinline__ void gload_lds16(const void* g, void* l) {
  __builtin_amdgcn_global_load_lds(
      (const __attribute__((address_space(1))) void*)g,
      (__attribute__((address_space(3))) void*)l, 16, 0, 0);
}

__global__ __launch_bounds__(256) void cvt_f32_bf16(const float* __restrict__ in,
                                                    unsigned short* __restrict__ out,
                                                    int n) {
  int i = (blockIdx.x * 256 + threadIdx.x) * 8;
  if (i >= n) return;
  float4 a = *(const float4*)(in + i);
  float4 b = *(const float4*)(in + i + 4);
  s16x8 o;
  o[0] = f2bf(a.x); o[1] = f2bf(a.y); o[2] = f2bf(a.z); o[3] = f2bf(a.w);
  o[4] = f2bf(b.x); o[5] = f2bf(b.y); o[6] = f2bf(b.z); o[7] = f2bf(b.w);
  *(s16x8*)(out + i) = o;
}

// C[M,N] = A[M,K] * W[N,K]^T, bf16 in, bf16 or f32 out. 128x128 tile, BK=64,
// 4 waves (2x2), 16x16x32 MFMA, global_load_lds staging (m97 structure).
template <bool OUT_F32>
__global__ __launch_bounds__(256, 2) void gemm_bt(const unsigned short* __restrict__ A,
                                                  const unsigned short* __restrict__ W,
                                                  void* __restrict__ Cout,
                                                  int M, int N, int K, int nbn) {
  __shared__ unsigned short As[128 * 64];
  __shared__ unsigned short Bs[128 * 64];
  const int bm = blockIdx.x / nbn, bn = blockIdx.x % nbn;
  const int tid = threadIdx.x;
  const int w = tid >> 6, lane = tid & 63;
  const int wr = w >> 1, wc = w & 1;
  const int lr = lane & 15, lk = lane >> 4;
  const int m0 = bm * 128, n0 = bn * 128;
  f32x4 acc[4][4] = {};

  for (int k0 = 0; k0 < K; k0 += 64) {
#pragma unroll
    for (int i = 0; i < 4; ++i) {
      const int base = i * 4096 + w * 1024;
      const int boff = base + lane * 16;
      const int row = boff >> 7;
      const int col = (boff >> 1) & 63;
      gload_lds16(A + (size_t)(m0 + row) * K + k0 + col, (char*)As + base);
      gload_lds16(W + (size_t)(n0 + row) * K + k0 + col, (char*)Bs + base);
    }
    __syncthreads();
#pragma unroll
    for (int kk = 0; kk < 2; ++kk) {
      s16x8 af[4], bfr[4];
#pragma unroll
      for (int m = 0; m < 4; ++m)
        af[m] = *(const s16x8*)((const char*)As + (wr * 64 + m * 16 + lr) * 128 + kk * 64 + lk * 16);
#pragma unroll
      for (int n = 0; n < 4; ++n)
        bfr[n] = *(const s16x8*)((const char*)Bs + (wc * 64 + n * 16 + lr) * 128 + kk * 64 + lk * 16);
#pragma unroll
      for (int m = 0; m < 4; ++m)
#pragma unroll
        for (int n = 0; n < 4; ++n)
          acc[m][n] = __builtin_amdgcn_mfma_f32_16x16x32_bf16(af[m], bfr[n], acc[m][n], 0, 0, 0);
    }
    __syncthreads();
  }
#pragma unroll
  for (int m = 0; m < 4; ++m)
#pragma unroll
    for (int n = 0; n < 4; ++n)
#pragma unroll
      for (int r = 0; r < 4; ++r) {
        const int row = m0 + wr * 64 + m * 16 + lk * 4 + r;
        const int col = n0 + wc * 64 + n * 16 + lr;
        if (OUT_F32)
          ((float*)Cout)[(size_t)row * N + col] = acc[m][n][r];
        else
          ((unsigned short*)Cout)[(size_t)row * N + col] = f2bf(acc[m][n][r]);
      }
}

// Transpose V out of qkv into VT[bh][d][s].
__global__ __launch_bounds__(256) void vtrans(const unsigned short* __restrict__ qkv,
                                              unsigned short* __restrict__ vt) {
  __shared__ unsigned short T[64][65];
  const int blk = blockIdx.x;
  const int st = blk & 31, bh = blk >> 5;
  const int h = bh & 15, b = bh >> 4;
  const int s0 = st * 64;
  const int tid = threadIdx.x;
#pragma unroll
  for (int i = 0; i < 2; ++i) {
    const int idx = tid + i * 256;
    const int sy = idx >> 3, tx = idx & 7;
    s16x8 v = *(const s16x8*)(qkv + (size_t)(b * S_LEN + s0 + sy) * QKV_LD + 2 * DM + h * HD + tx * 8);
#pragma unroll
    for (int j = 0; j < 8; ++j) T[tx * 8 + j][sy] = v[j];
  }
  __syncthreads();
#pragma unroll
  for (int i = 0; i < 2; ++i) {
    const int idx = tid + i * 256;
    const int d = idx >> 3, tx = idx & 7;
    s16x8 v;
#pragma unroll
    for (int j = 0; j < 8; ++j) v[j] = T[d][tx * 8 + j];
    *(s16x8*)(vt + (size_t)bh * (HD * S_LEN) + (size_t)d * S_LEN + s0 + tx * 8) = v;
  }
}

// Flash attention, causal. Block = 64 q-rows (4 waves x 16); all waves share
// each KV tile, staged into LDS via global_load_lds (m97 pattern, 2 barriers
// per tile). LDS 16B-chunk XOR swizzle (rule 21: linear dest, inverse-swizzled
// global source, swizzled read). Swapped QK^T (mfma(K,Q) -> S^T): in-lane
// softmax, q-index = lr.
__global__ __launch_bounds__(256, 4) void attn_fwd(const unsigned short* __restrict__ qkv,
                                                   const unsigned short* __restrict__ vt,
                                                   unsigned short* __restrict__ aout) {
  __shared__ unsigned short Ks[64 * 64];      // [s][d] 128B rows, swizzled chunks
  __shared__ unsigned short Vs[64 * 64];      // [d][s] 128B rows, swizzled chunks
  __shared__ unsigned short Pbuf[4][16][72];  // per-wave P re-layout
  const int bid = blockIdx.x;
  const int qt = 31 - (bid >> 5);  // heavy q-tiles first
  const int bh = bid & 31;
  const int h = bh & 15, b = bh >> 4;
  const int tid = threadIdx.x, w = tid >> 6, lane = tid & 63;
  const int lr = lane & 15, lk = lane >> 4;
  const int qb = qt * 64 + w * 16;
  const size_t rowbase = (size_t)b * S_LEN;
  const unsigned short* kbase = qkv + rowbase * QKV_LD + DM + h * HD;
  const unsigned short* vbase = vt + (size_t)bh * (HD * S_LEN);

  // staging lane geometry: each gload_lds16 instr covers 8 rows x 128B
  const int r8 = lane >> 3, c8 = lane & 7;
  const int celem = ((c8 ^ r8) << 3);  // inverse-swizzled element offset in row

  // swizzled read offsets (elements): e ^ ((row&7)<<3), row&7 == lr&7
  const int swz = (lr & 7) << 3;

  // Q fragments (B-operand), scaled by 0.125*log2(e) -> exp2-domain softmax
  s16x8 qf[2];
#pragma unroll
  for (int dk = 0; dk < 2; ++dk) {
    s16x8 q = *(const s16x8*)(qkv + (rowbase + qb + lr) * QKV_LD + h * HD + dk * 32 + lk * 8);
#pragma unroll
    for (int j = 0; j < 8; ++j)
      q[j] = (short)f2bf(bf2f((unsigned short)q[j]) * 0.18033688011112042f);
    qf[dk] = q;
  }

  f32x4 oacc[4] = {};
  float mr = -1e30f, ls = 0.f;

  for (int t = 0; t <= qt; ++t) {
    const int k0 = t * 64;
    // ---- stage K tile (from qkv, strided rows) + V^T tile (from vt) ----
    // 16 x 1KB chunks; wave w issues chunks [w*4, w*4+4)
#pragma unroll
    for (int jj = 0; jj < 4; ++jj) {
      const int j = w * 4 + jj;
      if (j < 8) {
        gload_lds16(kbase + (size_t)(k0 + j * 8 + r8) * QKV_LD + celem,
                    (char*)Ks + j * 1024);
      } else {
        gload_lds16(vbase + (size_t)((j - 8) * 8 + r8) * S_LEN + k0 + celem,
                    (char*)Vs + (j - 8) * 1024);
      }
    }
    __syncthreads();  // vmcnt(0) drain: tiles resident

    // ---- S^T = K Q^T : sf[n][r] = S[k = k0+n*16+lk*4+r][q = qb+lr] ----
    const bool dtile = (t == qt);
    f32x4 sf[4];
#pragma unroll
    for (int n = 0; n < 4; ++n) {
      if (!dtile || n <= w) {
        s16x8 kf0 = *(const s16x8*)(Ks + (n * 16 + lr) * 64 + ((lk * 8) ^ swz));
        s16x8 kf1 = *(const s16x8*)(Ks + (n * 16 + lr) * 64 + ((32 + lk * 8) ^ swz));
        f32x4 s = {};
        s = __builtin_amdgcn_mfma_f32_16x16x32_bf16(kf0, qf[0], s, 0, 0, 0);
        s = __builtin_amdgcn_mfma_f32_16x16x32_bf16(kf1, qf[1], s, 0, 0, 0);
        sf[n] = s;
      } else {
#pragma unroll
        for (int r = 0; r < 4; ++r) sf[n][r] = -1e30f;
      }
    }
    if (dtile) {  // diagonal subtile n==w: mask k > q, i.e. lk*4+r > lr
#pragma unroll
      for (int r = 0; r < 4; ++r)
        if (lk * 4 + r > lr) sf[w][r] = -1e30f;
    }
    // ---- online softmax (q per-lane = lr): in-lane reduce + 2 shfl ----
    float pm = sf[0][0];
#pragma unroll
    for (int n = 0; n < 4; ++n)
#pragma unroll
      for (int r = 0; r < 4; ++r) pm = fmaxf(pm, sf[n][r]);
    pm = fmaxf(pm, __shfl_xor(pm, 16));
    pm = fmaxf(pm, __shfl_xor(pm, 32));
    if (__any(pm > mr + 8.f)) {  // defer-max (T13)
      const float mn = fmaxf(mr, pm);
      const float al = __builtin_amdgcn_exp2f(mr - mn);
      mr = mn;
      ls *= al;
#pragma unroll
      for (int r = 0; r < 4; ++r) {
        const float alq = __shfl(al, lk * 4 + r);
#pragma unroll
        for (int n = 0; n < 4; ++n) oacc[n][r] *= alq;
      }
    }
    float rs = 0.f;
#pragma unroll
    for (int n = 0; n < 4; ++n)
#pragma unroll
      for (int r = 0; r < 4; ++r) {
        const float p = __builtin_amdgcn_exp2f(sf[n][r] - mr);
        sf[n][r] = p;
        rs += p;
      }
    rs += __shfl_xor(rs, 16);
    rs += __shfl_xor(rs, 32);
    ls += rs;
    // pack P -> Pbuf[q=lr][k] (positive values: round-half-up ~= RNE)
#pragma unroll
    for (int n = 0; n < 4; ++n) {
      union { float f; unsigned u; } c0, c1, c2, c3;
      c0.f = sf[n][0]; c1.f = sf[n][1]; c2.f = sf[n][2]; c3.f = sf[n][3];
      uint2 pk;
      pk.x = ((c0.u + 0x8000u) >> 16) | (((c1.u + 0x8000u) >> 16) << 16);
      pk.y = ((c2.u + 0x8000u) >> 16) | (((c3.u + 0x8000u) >> 16) << 16);
      *(uint2*)&Pbuf[w][lr][n * 16 + lk * 4] = pk;
    }
    // ---- O += P V : A = P rows (Pbuf), B = V^T rows (Vs, swizzled) ----
#pragma unroll
    for (int kk = 0; kk < 2; ++kk) {
      s16x8 pf = *(const s16x8*)&Pbuf[w][lr][kk * 32 + lk * 8];
#pragma unroll
      for (int n = 0; n < 4; ++n) {
        s16x8 vf = *(const s16x8*)(Vs + (n * 16 + lr) * 64 + ((kk * 32 + lk * 8) ^ swz));
        oacc[n] = __builtin_amdgcn_mfma_f32_16x16x32_bf16(pf, vf, oacc[n], 0, 0, 0);
      }
    }
    __syncthreads();  // protect Ks/Vs before next stage
  }

  // epilogue: O/l ; l is in q=lr domain, O rows are q=lk*4+r
  const float rl = __builtin_amdgcn_rcpf(ls);
#pragma unroll
  for (int r = 0; r < 4; ++r) {
    const float rlq = __shfl(rl, lk * 4 + r);
#pragma unroll
    for (int n = 0; n < 4; ++n)
      aout[(rowbase + qb + lk * 4 + r) * DM + h * HD + n * 16 + lr] = f2bf(oacc[n][r] * rlq);
  }
}

extern "C" void kernel_launch(void* const* d_in, const int* in_sizes, int n_in,
                              void* d_out, int out_size, void* d_ws, size_t ws_size,
                              hipStream_t stream) {
  const float* x = (const float*)d_in[0];      // [2,2048,1024]
  const float* wqkv = (const float*)d_in[1];   // [3072,1024]
  const float* wproj = (const float*)d_in[2];  // [1024,1024]
  float* out = (float*)d_out;                  // [2,2048,1024] f32

  char* ws = (char*)d_ws;
  unsigned short* xb = (unsigned short*)ws;                     // dead after gemm1
  unsigned short* wqkvb = (unsigned short*)(ws + (8u << 20));   // dead after gemm1
  unsigned short* wprojb = (unsigned short*)(ws + (14u << 20)); // written after attn
  unsigned short* vtb = (unsigned short*)ws;                    // overlays xb/wqkvb
  unsigned short* qkvb = (unsigned short*)(ws + (16u << 20));
  unsigned short* attnb = (unsigned short*)(ws + (40u << 20));

  cvt_f32_bf16<<<2048, 256, 0, stream>>>(x, xb, 4096 * 1024);
  cvt_f32_bf16<<<1536, 256, 0, stream>>>(wqkv, wqkvb, 3072 * 1024);

  gemm_bt<false><<<32 * 24, 256, 0, stream>>>(xb, wqkvb, qkvb, 4096, 3072, 1024, 24);
  vtrans<<<1024, 256, 0, stream>>>(qkvb, vtb);
  attn_fwd<<<1024, 256, 0, stream>>>(qkvb, vtb, attnb);
  cvt_f32_bf16<<<512, 256, 0, stream>>>(wproj, wprojb, 1024 * 1024);
  gemm_bt<true><<<32 * 8, 256, 0, stream>>>(attnb, wprojb, out, 4096, 1024, 1024, 8);
}